// Round 3
// baseline (153.114 us; speedup 1.0000x reference)
//
#include <hip/hip_runtime.h>
#include <cstdint>

#define DEV __device__ __forceinline__

typedef __bf16  bf16x8 __attribute__((ext_vector_type(8)));
typedef short   s16x8  __attribute__((ext_vector_type(8)));
typedef float   f32x4  __attribute__((ext_vector_type(4)));

#define QSCALE 0.18033688011112042f   /* 0.125 * log2(e) */
#define MOFF   17.312340490667560f    /* 12 * log2(e)    */

// fp32 -> bf16 round-to-nearest-even
DEV unsigned short f2bf(float f){
  union { float f; unsigned u; } v; v.f = f;
  unsigned r = v.u + 0x7fffu + ((v.u >> 16) & 1u);
  return (unsigned short)(r >> 16);
}

// pack two positive f32 -> 2 bf16 (round-half-up) in one dword: lo in low16
DEV unsigned pk2(float lo, float hi){
  unsigned a = __builtin_bit_cast(unsigned, lo) + 0x8000u;
  unsigned b = __builtin_bit_cast(unsigned, hi) + 0x8000u;
  return __builtin_amdgcn_perm(b, a, 0x07060302);  // {hi16(b),hi16(a)}
}

// async global->LDS, 16B per lane; LDS dest must be uniform_base + lane*16
DEV void gl2lds16(const void* g, void* l){
  __builtin_amdgcn_global_load_lds((__attribute__((address_space(1))) void*)(void*)(g),
                                   (__attribute__((address_space(3))) void*)(l), 16, 0, 0);
}

DEV f32x4 mfma16(bf16x8 a, bf16x8 b, f32x4 c){
  return __builtin_amdgcn_mfma_f32_16x16x32_bf16(a, b, c, 0, 0, 0);
}

// ---------------------------------------------------------------- prep (merged)
// blocks 0..1535: cast x; 1536: rel tables (*8, rpwb zero-padded to 64 rows);
// 1537..3264: transpose w_qkv; 3265..3840: transpose w_out.
__global__ __launch_bounds__(256) void prep_kernel(const float* __restrict__ x,
                                                   short* __restrict__ xb,
                                                   const float* __restrict__ rph,
                                                   const float* __restrict__ rpw,
                                                   short* __restrict__ rphb,
                                                   short* __restrict__ rpwb,
                                                   const float* __restrict__ w_qkv,
                                                   short* __restrict__ wqT,
                                                   const float* __restrict__ w_out,
                                                   short* __restrict__ woT){
  __shared__ float tb[32][33];
  int b = blockIdx.x;
  if (b < 1536){
    int i = b * 256 + threadIdx.x;
    const float4* in4 = (const float4*)x;
    float4 f0 = in4[i*2], f1 = in4[i*2+1];
    s16x8 o;
    o[0]=(short)f2bf(f0.x); o[1]=(short)f2bf(f0.y); o[2]=(short)f2bf(f0.z); o[3]=(short)f2bf(f0.w);
    o[4]=(short)f2bf(f1.x); o[5]=(short)f2bf(f1.y); o[6]=(short)f2bf(f1.z); o[7]=(short)f2bf(f1.w);
    *(s16x8*)(xb + i*8) = o;
  } else if (b == 1536){
    int t = threadIdx.x;
    for (int j = 0; j < 16; j++){
      int idx = t*16 + j;
      if (idx < 4032){
        rphb[idx] = (short)f2bf(rph[idx] * 8.f);   // *8 compensates q pre-scale
        rpwb[idx] = (short)f2bf(rpw[idx] * 8.f);
      } else if (idx < 4096){
        rpwb[idx] = 0;                             // pad row 63 (flash A-frag safety)
      }
    }
  } else {
    const float* in; short* out; int R, C, bx, by;
    if (b < 3265){ int t = b - 1537; in = w_qkv; out = wqT; R = 768; C = 2304; bx = t % 72; by = t / 72; }
    else         { int t = b - 3265; in = w_out; out = woT; R = 768; C = 768;  bx = t % 24; by = t / 24; }
    int tx = threadIdx.x & 31, ty = threadIdx.x >> 5;
    int c0 = bx * 32, r0 = by * 32;
    for (int i = 0; i < 4; i++)
      tb[ty + i*8][tx] = in[(r0 + ty + i*8)*C + c0 + tx];
    __syncthreads();
    for (int i = 0; i < 4; i++)
      out[(c0 + ty + i*8)*R + r0 + tx] = (short)f2bf(tb[tx][ty + i*8]);
  }
}

// ---------------------------------------------------------------- QKV GEMM
// 128x96 tiles -> 768 blocks = exactly 3/CU.  T1 XCD banding (8x12 tile
// rectangle per XCD; A 1.6MB + B 1.7MB fits 4MB L2).
// q stored PRE-SCALED by 0.125*log2e; v written DIRECTLY TRANSPOSED.
__global__ __launch_bounds__(256) void qkv_gemm_kernel(const short* __restrict__ xb,
                                                       const short* __restrict__ wqT,
                                                       short* __restrict__ qb,
                                                       short* __restrict__ kb,
                                                       short* __restrict__ vtb){
  __shared__ __align__(16) short As[128*64];
  __shared__ __align__(16) short Bs[96*64];
  const int tid = threadIdx.x, lane = tid & 63, wv = tid >> 6;
  const int quad = lane >> 4, mi = lane & 15;
  const int flat = blockIdx.x + (blockIdx.y << 5);
  const int xcd = flat & 7, s = flat >> 3;           // s in 0..95
  const int bx = (xcd & 3)*8 + (s & 7);              // 0..31
  const int by = (xcd >> 2)*12 + (s >> 3);           // 0..23
  const int m0 = bx * 128, n0 = by * 96;
  const int wrow = wv >> 1, wcol = wv & 1;
  const int srow = lane >> 3, scs = lane & 7;
  const int sc = scs ^ (srow & 7);
  f32x4 acc[4][3] = {};
  for (int k0 = 0; k0 < 768; k0 += 64){
    __syncthreads();
    for (int i = 0; i < 4; i++){
      int rbase = i*32 + wv*8;
      int row = rbase + srow;
      gl2lds16(xb + (m0+row)*768 + k0 + sc*8, As + rbase*64 + lane*8);
    }
    for (int i = 0; i < 3; i++){
      int rbase = i*32 + wv*8;
      int row = rbase + srow;
      gl2lds16(wqT + (n0+row)*768 + k0 + sc*8, Bs + rbase*64 + lane*8);
    }
    __syncthreads();
    bf16x8 a[2][4], b[2][3];
#pragma unroll
    for (int kk = 0; kk < 2; kk++){
      int ccs = ((quad + kk*4) ^ (mi & 7)) * 8;
      for (int mt = 0; mt < 4; mt++) a[kk][mt] = *(const bf16x8*)(As + (wrow*64 + mt*16 + mi)*64 + ccs);
      for (int nt = 0; nt < 3; nt++) b[kk][nt] = *(const bf16x8*)(Bs + (wcol*48 + nt*16 + mi)*64 + ccs);
    }
#pragma unroll
    for (int kk = 0; kk < 2; kk++)
      for (int mt = 0; mt < 4; mt++)
        for (int nt = 0; nt < 3; nt++)
          acc[mt][nt] = mfma16(a[kk][mt], b[kk][nt], acc[mt][nt]);
  }
  const int which = n0 / 768;                    // uniform per block (768%96==0)
  if (which == 2){
    for (int nt = 0; nt < 3; nt++){
      int j = n0 + wcol*48 + nt*16 + mi;
      int rem = j % 768;
      int head = rem >> 6, d = rem & 63;
      for (int mt = 0; mt < 4; mt++)
        for (int r = 0; r < 4; r++){
          int m = m0 + wrow*64 + mt*16 + quad*4 + r;
          int bh = (m >> 10)*12 + head;
          vtb[((bh*64 + d) << 10) + (m & 1023)] = (short)f2bf(acc[mt][nt][r]);
        }
    }
  } else {
    const float qs = (which == 0) ? QSCALE : 1.0f;
    short* dst = (which == 0) ? qb : kb;
    for (int nt = 0; nt < 3; nt++){
      int j = n0 + wcol*48 + nt*16 + mi;
      int rem = j % 768;
      int head = rem >> 6, d = rem & 63;
      for (int mt = 0; mt < 4; mt++)
        for (int r = 0; r < 4; r++){
          int m = m0 + wrow*64 + mt*16 + quad*4 + r;
          int bh = (m >> 10)*12 + head;
          dst[((bh << 10) + (m & 1023))*64 + d] = (short)f2bf(acc[mt][nt][r] * qs);
        }
    }
  }
}

// ---------------------------------------------------------------- flash attention
// R8-champion loop structure (single K/V buffer, stage->barrier->compute->
// barrier; S^T; fixed-max softmax; exp2 folding; deferred l-reduction).
// rel_h computed in-kernel (4 MFMAs on register-resident q frags).
// NEW: rel_w ALSO computed in-kernel -> relw_kernel + relW buffer deleted.
//   Direct MFMA is impossible (table row w(qrow)-kw+31 depends on both
//   output row and col), so compute the full table E[j'][qrow] =
//   sum_d rpw8[j'] . q[qrow] for j'=0..63 (8 MFMAs/wave, B = qf regs),
//   park in LDS, then gather rw[s][r] = E[w+31-kw][qrow] per lane
//   (same-wave columns -> no barrier).  Es (16KB) overlays dead Qt+rWs;
//   extra barrier after qf loads guards the overwrite.  LDS still 48KB.
// T1 XCD swizzle: XCD c owns bh in [c*6, c*6+6) (K/V L2-resident).
__global__ __launch_bounds__(256, 3) void flash_kernel(const short* __restrict__ qb,
                                                       const short* __restrict__ kb,
                                                       const short* __restrict__ vtb,
                                                       const short* __restrict__ rphb,
                                                       const short* __restrict__ rpwb,
                                                       short* __restrict__ ao){
  __shared__ __align__(16) char QE[16384];    // Qt (first 8KB) / Es f32[64][64]
  __shared__ __align__(16) short Kt[64*64];
  __shared__ __align__(16) short Vt[64*64];   // [d][key], swizzled
  __shared__ __align__(16) short Pt[64*64];   // [qrow][key], swizzled
  __shared__ __align__(16) float rHs[32*64];  // [kh][qrow], computed in-kernel
  short* Qt = (short*)QE;
  float* Es = (float*)QE;
  const int tid = threadIdx.x, lane = tid & 63, wv = tid >> 6;
  const int quad = lane >> 4, mi = lane & 15;
  // XCD-aware remap (grid 16 x 48, x fastest; 768 % 8 == 0)
  const int flat = blockIdx.x + (blockIdx.y << 4);
  const int nw = (flat & 7)*96 + (flat >> 3);
  const int bh = nw >> 4, n0 = (nw & 15) << 6;
  const int sw0 = (quad ^ (mi & 7)) * 8;
  const int sw1 = ((quad + 4) ^ (mi & 7)) * 8;
  const int qrow = wv*16 + mi;
  const int srow = lane >> 3;

  const short* kg = kb  + bh*1024*64;
  const short* vg = vtb + bh*64*1024;

  {
    const short* qg = qb + (bh*1024 + n0)*64;
    for (int i = 0; i < 2; i++){
      int slab = wv*2 + i, rbase = slab*8;
      int row = rbase + srow;
      int c = (lane & 7) ^ (row & 7);
      gl2lds16(qg + row*64 + c*8, Qt + rbase*64 + lane*8);
    }
  }
  __syncthreads();

  bf16x8 qf0 = *(const bf16x8*)(Qt + qrow*64 + sw0);
  bf16x8 qf1 = *(const bf16x8*)(Qt + qrow*64 + sw1);

  // rel_h -> rHs (wave-private columns wv*16+mi); h uniform per wave
  {
    int h = (n0 + wv*16) >> 5;
    const short* rp = rphb + (h + 31 - mi)*64;       // A row mi <-> kh = khb*16+mi
#pragma unroll
    for (int khb = 0; khb < 2; khb++){
      const short* rk = rp - khb*1024;               // -16 rows
      bf16x8 a0 = *(const bf16x8*)(rk + quad*8);
      bf16x8 a1 = *(const bf16x8*)(rk + 32 + quad*8);
      f32x4 c = {};
      c = mfma16(a0, qf0, c);
      c = mfma16(a1, qf1, c);
      for (int r = 0; r < 4; r++)
        rHs[(khb*16 + quad*4 + r)*64 + wv*16 + mi] = c[r] - MOFF;
    }
  }

  __syncthreads();   // all waves done reading Qt before Es overwrites it

  // rel_w table: E[j'][qrow] = sum_d rpw8[j'][d] * q[qrow][d], j' = 0..63
  // (row 63 is zero-padded garbage, never read).  A row mi <-> j' = jt*16+mi.
#pragma unroll
  for (int jt = 0; jt < 4; jt++){
    const short* rr = rpwb + (jt*16 + mi)*64;
    bf16x8 a0 = *(const bf16x8*)(rr + quad*8);
    bf16x8 a1 = *(const bf16x8*)(rr + 32 + quad*8);
    f32x4 c = {};
    c = mfma16(a0, qf0, c);
    c = mfma16(a1, qf1, c);
    for (int r = 0; r < 4; r++)
      Es[(jt*16 + quad*4 + r)*64 + qrow] = c[r];
  }
  // gather per-lane rel_w (reads own-wave columns -> same-wave DS ordering)
  float rw[2][4];
  {
    int w31 = (qrow & 31) + 31;                      // w = (n0+qrow)&31, n0 mult of 64
#pragma unroll
    for (int s = 0; s < 2; s++)
      for (int r = 0; r < 4; r++)
        rw[s][r] = Es[(w31 - (s*16 + quad*4 + r))*64 + qrow];
  }

  f32x4 O[4] = {};
  float l_ = 0.f;

  for (int step = 0; step < 16; step++){
    {
      const short* kt = kg + step*64*64;
      for (int i = 0; i < 2; i++){
        int slab = wv*2 + i, rbase = slab*8;
        int row = rbase + srow;
        int c = (lane & 7) ^ (row & 7);
        gl2lds16(kt + row*64 + c*8, Kt + rbase*64 + lane*8);
        gl2lds16(vg + row*1024 + step*64 + c*8, Vt + rbase*64 + lane*8);
      }
    }
    __syncthreads();

    // S^T: A = K-frag (rows=keys), B = Q-frag (cols=qrows)
    f32x4 S[4];
#pragma unroll
    for (int nt = 0; nt < 4; nt++){
      bf16x8 kf0 = *(const bf16x8*)(Kt + (nt*16 + mi)*64 + sw0);
      bf16x8 kf1 = *(const bf16x8*)(Kt + (nt*16 + mi)*64 + sw1);
      f32x4 c = {};
      c = mfma16(kf0, qf0, c);
      c = mfma16(kf1, qf1, c);
      S[nt] = c;   // lane: qrow fixed, key = nt*16 + quad*4 + r
    }
    // p = exp2(S + kh' + rw')  (M folded into kh'); conflict-free [kh][qrow] reads
    float kh0 = rHs[(2*step)*64 + qrow];
    float kh1 = rHs[(2*step + 1)*64 + qrow];
#pragma unroll
    for (int nt = 0; nt < 4; nt++){
      float kh = (nt & 2) ? kh1 : kh0;
      for (int r = 0; r < 4; r++){
        float p = __builtin_amdgcn_exp2f(S[nt][r] + kh + rw[nt & 1][r]);
        S[nt][r] = p;
        l_ += p;
      }
    }
    // P -> LDS: row qrow, cols nt*16+quad*4+{0..3}: 4x ds_write_b64, swizzled
#pragma unroll
    for (int nt = 0; nt < 4; nt++){
      unsigned u0 = pk2(S[nt][0], S[nt][1]);
      unsigned u1 = pk2(S[nt][2], S[nt][3]);
      int chunk = (2*nt + (quad >> 1)) ^ (mi & 7);
      uint2 uu; uu.x = u0; uu.y = u1;
      *(uint2*)(Pt + qrow*64 + chunk*8 + (quad & 1)*4) = uu;
    }
    // PV (wave-private Pt rows: same-wave DS ordering, no barrier needed)
    bf16x8 p0 = *(const bf16x8*)(Pt + qrow*64 + sw0);
    bf16x8 p1 = *(const bf16x8*)(Pt + qrow*64 + sw1);
#pragma unroll
    for (int t = 0; t < 4; t++){
      bf16x8 v0 = *(const bf16x8*)(Vt + (t*16 + mi)*64 + sw0);
      bf16x8 v1 = *(const bf16x8*)(Vt + (t*16 + mi)*64 + sw1);
      O[t] = mfma16(p0, v0, O[t]);
      O[t] = mfma16(p1, v1, O[t]);
    }
    __syncthreads();   // all waves done with Kt/Vt before next stage
  }

  l_ += __shfl_xor(l_, 16, 64);
  l_ += __shfl_xor(l_, 32, 64);
  float inv[4];
#pragma unroll
  for (int r = 0; r < 4; r++) inv[r] = 1.f / __shfl(l_, quad*4 + r, 64);
  int b_ = bh / 12, head = bh % 12;
#pragma unroll
  for (int t = 0; t < 4; t++)
    for (int r = 0; r < 4; r++){
      int n = n0 + wv*16 + quad*4 + r;
      ao[(b_*1024 + n)*768 + head*64 + t*16 + mi] = (short)f2bf(O[t][r] * inv[r]);
    }
}

// ---------------------------------------------------------------- out proj
// 64x96 tiles -> grid 64x8 = 512 blocks = exactly 2/CU.
__global__ __launch_bounds__(256) void proj_kernel(const short* __restrict__ ao,
                                                   const short* __restrict__ woT,
                                                   const float* __restrict__ bias,
                                                   float* __restrict__ out){
  __shared__ __align__(16) short As[64*64];
  __shared__ __align__(16) short Bs[96*64];
  const int tid = threadIdx.x, lane = tid & 63, wv = tid >> 6;
  const int quad = lane >> 4, mi = lane & 15;
  const int m0 = blockIdx.x * 64, n0 = blockIdx.y * 96;
  const int wrow = wv >> 1, wcol = wv & 1;         // wave tile: 32 rows x 48 cols
  const int srow = lane >> 3, sc = (lane & 7) ^ (srow & 7);
  f32x4 acc[2][3] = {};
  for (int k0 = 0; k0 < 768; k0 += 64){
    __syncthreads();
    for (int i = 0; i < 2; i++){
      int rbase = i*32 + wv*8, row = rbase + srow;
      gl2lds16(ao + (m0+row)*768 + k0 + sc*8, As + rbase*64 + lane*8);
    }
    for (int i = 0; i < 3; i++){
      int rbase = i*32 + wv*8, row = rbase + srow;
      gl2lds16(woT + (n0+row)*768 + k0 + sc*8, Bs + rbase*64 + lane*8);
    }
    __syncthreads();
    bf16x8 a[2][2], b[2][3];
#pragma unroll
    for (int kk = 0; kk < 2; kk++){
      int ccs = ((quad + kk*4) ^ (mi & 7)) * 8;
      for (int mt = 0; mt < 2; mt++) a[kk][mt] = *(const bf16x8*)(As + (wrow*32 + mt*16 + mi)*64 + ccs);
      for (int nt = 0; nt < 3; nt++) b[kk][nt] = *(const bf16x8*)(Bs + (wcol*48 + nt*16 + mi)*64 + ccs);
    }
#pragma unroll
    for (int kk = 0; kk < 2; kk++)
      for (int mt = 0; mt < 2; mt++)
        for (int nt = 0; nt < 3; nt++)
          acc[mt][nt] = mfma16(a[kk][mt], b[kk][nt], acc[mt][nt]);
  }
  for (int nt = 0; nt < 3; nt++){
    int j = n0 + wcol*48 + nt*16 + mi;
    float bj = bias[j];
    for (int mt = 0; mt < 2; mt++)
      for (int r = 0; r < 4; r++){
        int m = m0 + wrow*32 + mt*16 + quad*4 + r;
        out[m*768 + j] = acc[mt][nt][r] + bj;
      }
  }
}

// ---------------------------------------------------------------- launch
extern "C" void kernel_launch(void* const* d_in, const int* in_sizes, int n_in,
                              void* d_out, int out_size, void* d_ws, size_t ws_size,
                              hipStream_t stream){
  const float* x     = (const float*)d_in[0];
  const float* w_qkv = (const float*)d_in[1];
  const float* w_out = (const float*)d_in[2];
  const float* b_out = (const float*)d_in[3];
  const float* rph   = (const float*)d_in[4];
  const float* rpw   = (const float*)d_in[5];
  float* out = (float*)d_out;
  char* ws = (char*)d_ws;
  short* xb    = (short*)(ws + 0);          // 4096x768 bf16 (reused as ao after qkv)
  short* wqT   = (short*)(ws + 6291456);    // 2304x768 bf16
  short* woT   = (short*)(ws + 9830400);    // 768x768 bf16
  short* qb    = (short*)(ws + 11010048);   // 48x1024x64 bf16 (pre-scaled 0.125*log2e)
  short* kb    = (short*)(ws + 17301504);   // 48x1024x64 bf16
  short* vtb   = (short*)(ws + 29884416);   // 48x64x1024 bf16 (written by qkv, transposed)
  short* rphb  = (short*)(ws + 48758784);   // 63x64 bf16 (*8)
  short* rpwb  = (short*)(ws + 48775168);   // 64x64 bf16 (*8, row 63 zeroed)
  short* ao    = xb;                        // reuse

  prep_kernel<<<3841, 256, 0, stream>>>(x, xb, rph, rpw, rphb, rpwb, w_qkv, wqT, w_out, woT);
  qkv_gemm_kernel<<<dim3(32, 24), 256, 0, stream>>>(xb, wqT, qb, kb, vtb);
  flash_kernel<<<dim3(16, 48), 256, 0, stream>>>(qb, kb, vtb, rphb, rpwb, ao);
  proj_kernel<<<dim3(64, 8), 256, 0, stream>>>(ao, woT, b_out, out);
}

// Round 4
// 151.040 us; speedup vs baseline: 1.0137x; 1.0137x over previous
//
#include <hip/hip_runtime.h>
#include <cstdint>

#define DEV __device__ __forceinline__

typedef __bf16  bf16x8 __attribute__((ext_vector_type(8)));
typedef short   s16x8  __attribute__((ext_vector_type(8)));
typedef float   f32x4  __attribute__((ext_vector_type(4)));

#define QSCALE 0.18033688011112042f   /* 0.125 * log2(e) */
#define MOFF   17.312340490667560f    /* 12 * log2(e)    */

// fp32 -> bf16 round-to-nearest-even
DEV unsigned short f2bf(float f){
  union { float f; unsigned u; } v; v.f = f;
  unsigned r = v.u + 0x7fffu + ((v.u >> 16) & 1u);
  return (unsigned short)(r >> 16);
}

// pack two positive f32 -> 2 bf16 (round-half-up) in one dword: lo in low16
DEV unsigned pk2(float lo, float hi){
  unsigned a = __builtin_bit_cast(unsigned, lo) + 0x8000u;
  unsigned b = __builtin_bit_cast(unsigned, hi) + 0x8000u;
  return __builtin_amdgcn_perm(b, a, 0x07060302);  // {hi16(b),hi16(a)}
}

// async global->LDS, 16B per lane; LDS dest must be uniform_base + lane*16
DEV void gl2lds16(const void* g, void* l){
  __builtin_amdgcn_global_load_lds((__attribute__((address_space(1))) void*)(void*)(g),
                                   (__attribute__((address_space(3))) void*)(l), 16, 0, 0);
}

DEV f32x4 mfma16(bf16x8 a, bf16x8 b, f32x4 c){
  return __builtin_amdgcn_mfma_f32_16x16x32_bf16(a, b, c, 0, 0, 0);
}

// ---------------------------------------------------------------- prep (merged)
// blocks 0..1535: cast x; 1536: rel tables (*8, rpwb zero-padded to 64 rows);
// 1537..3264: transpose w_qkv; 3265..3840: transpose w_out.
__global__ __launch_bounds__(256) void prep_kernel(const float* __restrict__ x,
                                                   short* __restrict__ xb,
                                                   const float* __restrict__ rph,
                                                   const float* __restrict__ rpw,
                                                   short* __restrict__ rphb,
                                                   short* __restrict__ rpwb,
                                                   const float* __restrict__ w_qkv,
                                                   short* __restrict__ wqT,
                                                   const float* __restrict__ w_out,
                                                   short* __restrict__ woT){
  __shared__ float tb[32][33];
  int b = blockIdx.x;
  if (b < 1536){
    int i = b * 256 + threadIdx.x;
    const float4* in4 = (const float4*)x;
    float4 f0 = in4[i*2], f1 = in4[i*2+1];
    s16x8 o;
    o[0]=(short)f2bf(f0.x); o[1]=(short)f2bf(f0.y); o[2]=(short)f2bf(f0.z); o[3]=(short)f2bf(f0.w);
    o[4]=(short)f2bf(f1.x); o[5]=(short)f2bf(f1.y); o[6]=(short)f2bf(f1.z); o[7]=(short)f2bf(f1.w);
    *(s16x8*)(xb + i*8) = o;
  } else if (b == 1536){
    int t = threadIdx.x;
    for (int j = 0; j < 16; j++){
      int idx = t*16 + j;
      if (idx < 4032){
        rphb[idx] = (short)f2bf(rph[idx] * 8.f);   // *8 compensates q pre-scale
        rpwb[idx] = (short)f2bf(rpw[idx] * 8.f);
      } else if (idx < 4096){
        rpwb[idx] = 0;                             // pad row 63 (flash A-frag safety)
      }
    }
  } else {
    const float* in; short* out; int R, C, bx, by;
    if (b < 3265){ int t = b - 1537; in = w_qkv; out = wqT; R = 768; C = 2304; bx = t % 72; by = t / 72; }
    else         { int t = b - 3265; in = w_out; out = woT; R = 768; C = 768;  bx = t % 24; by = t / 24; }
    int tx = threadIdx.x & 31, ty = threadIdx.x >> 5;
    int c0 = bx * 32, r0 = by * 32;
    for (int i = 0; i < 4; i++)
      tb[ty + i*8][tx] = in[(r0 + ty + i*8)*C + c0 + tx];
    __syncthreads();
    for (int i = 0; i < 4; i++)
      out[(c0 + ty + i*8)*R + r0 + tx] = (short)f2bf(tb[tx][ty + i*8]);
  }
}

// ---------------------------------------------------------------- QKV GEMM
// 128x96 tiles -> 768 blocks = exactly 3/CU.  T1 XCD banding (8x12 tile
// rectangle per XCD; A 1.6MB + B 1.7MB fits 4MB L2).
// q stored PRE-SCALED by 0.125*log2e; v written DIRECTLY TRANSPOSED.
__global__ __launch_bounds__(256) void qkv_gemm_kernel(const short* __restrict__ xb,
                                                       const short* __restrict__ wqT,
                                                       short* __restrict__ qb,
                                                       short* __restrict__ kb,
                                                       short* __restrict__ vtb){
  __shared__ __align__(16) short As[128*64];
  __shared__ __align__(16) short Bs[96*64];
  const int tid = threadIdx.x, lane = tid & 63, wv = tid >> 6;
  const int quad = lane >> 4, mi = lane & 15;
  const int flat = blockIdx.x + (blockIdx.y << 5);
  const int xcd = flat & 7, s = flat >> 3;           // s in 0..95
  const int bx = (xcd & 3)*8 + (s & 7);              // 0..31
  const int by = (xcd >> 2)*12 + (s >> 3);           // 0..23
  const int m0 = bx * 128, n0 = by * 96;
  const int wrow = wv >> 1, wcol = wv & 1;
  const int srow = lane >> 3, scs = lane & 7;
  const int sc = scs ^ (srow & 7);
  f32x4 acc[4][3] = {};
  for (int k0 = 0; k0 < 768; k0 += 64){
    __syncthreads();
    for (int i = 0; i < 4; i++){
      int rbase = i*32 + wv*8;
      int row = rbase + srow;
      gl2lds16(xb + (m0+row)*768 + k0 + sc*8, As + rbase*64 + lane*8);
    }
    for (int i = 0; i < 3; i++){
      int rbase = i*32 + wv*8;
      int row = rbase + srow;
      gl2lds16(wqT + (n0+row)*768 + k0 + sc*8, Bs + rbase*64 + lane*8);
    }
    __syncthreads();
    bf16x8 a[2][4], b[2][3];
#pragma unroll
    for (int kk = 0; kk < 2; kk++){
      int ccs = ((quad + kk*4) ^ (mi & 7)) * 8;
      for (int mt = 0; mt < 4; mt++) a[kk][mt] = *(const bf16x8*)(As + (wrow*64 + mt*16 + mi)*64 + ccs);
      for (int nt = 0; nt < 3; nt++) b[kk][nt] = *(const bf16x8*)(Bs + (wcol*48 + nt*16 + mi)*64 + ccs);
    }
#pragma unroll
    for (int kk = 0; kk < 2; kk++)
      for (int mt = 0; mt < 4; mt++)
        for (int nt = 0; nt < 3; nt++)
          acc[mt][nt] = mfma16(a[kk][mt], b[kk][nt], acc[mt][nt]);
  }
  const int which = n0 / 768;                    // uniform per block (768%96==0)
  if (which == 2){
    for (int nt = 0; nt < 3; nt++){
      int j = n0 + wcol*48 + nt*16 + mi;
      int rem = j % 768;
      int head = rem >> 6, d = rem & 63;
      for (int mt = 0; mt < 4; mt++)
        for (int r = 0; r < 4; r++){
          int m = m0 + wrow*64 + mt*16 + quad*4 + r;
          int bh = (m >> 10)*12 + head;
          vtb[((bh*64 + d) << 10) + (m & 1023)] = (short)f2bf(acc[mt][nt][r]);
        }
    }
  } else {
    const float qs = (which == 0) ? QSCALE : 1.0f;
    short* dst = (which == 0) ? qb : kb;
    for (int nt = 0; nt < 3; nt++){
      int j = n0 + wcol*48 + nt*16 + mi;
      int rem = j % 768;
      int head = rem >> 6, d = rem & 63;
      for (int mt = 0; mt < 4; mt++)
        for (int r = 0; r < 4; r++){
          int m = m0 + wrow*64 + mt*16 + quad*4 + r;
          int bh = (m >> 10)*12 + head;
          dst[((bh << 10) + (m & 1023))*64 + d] = (short)f2bf(acc[mt][nt][r] * qs);
        }
    }
  }
}

// ---------------------------------------------------------------- flash attention
// NEW (this round): double-buffered K/V main loop (T3 minimum 2-phase).
// After the prologue the 16KB Qt/Es region is DEAD (qf, rw, rHs consumed
// into registers / wave-private LDS), so it becomes K/V buffer 1 for free:
// LDS stays 48KB -> 3 blocks/CU.  Loop: issue stage(step+1) into buf^1,
// compute buf, ONE barrier (vmcnt(0) drain lands after ~1000cy of compute
// -> K/V fetch latency hidden), swap.  Written as 8 pairs so buffer
// pointers are compile-time constant.  Barriers/step: 2 -> 1.
// rel_h + rel_w computed in-kernel (MFMAs on register-resident q frags).
// T1 XCD swizzle: XCD c owns bh in [c*6, c*6+6) (K/V L2-resident).
__global__ __launch_bounds__(256, 3) void flash_kernel(const short* __restrict__ qb,
                                                       const short* __restrict__ kb,
                                                       const short* __restrict__ vtb,
                                                       const short* __restrict__ rphb,
                                                       const short* __restrict__ rpwb,
                                                       short* __restrict__ ao){
  __shared__ __align__(16) char QE[16384];    // Qt (8KB) / Es f32[64][64] / {Kt1,Vt1}
  __shared__ __align__(16) short Kt0[64*64];
  __shared__ __align__(16) short Vt0[64*64];  // [d][key], swizzled
  __shared__ __align__(16) short Pt[64*64];   // [qrow][key], swizzled
  __shared__ __align__(16) float rHs[32*64];  // [kh][qrow], computed in-kernel
  short* Qt  = (short*)QE;
  float* Es  = (float*)QE;
  short* Kt1 = (short*)QE;                    // buffer 1 overlays dead Qt/Es
  short* Vt1 = (short*)(QE + 8192);
  const int tid = threadIdx.x, lane = tid & 63, wv = tid >> 6;
  const int quad = lane >> 4, mi = lane & 15;
  // XCD-aware remap (grid 16 x 48, x fastest; 768 % 8 == 0)
  const int flat = blockIdx.x + (blockIdx.y << 4);
  const int nw = (flat & 7)*96 + (flat >> 3);
  const int bh = nw >> 4, n0 = (nw & 15) << 6;
  const int sw0 = (quad ^ (mi & 7)) * 8;
  const int sw1 = ((quad + 4) ^ (mi & 7)) * 8;
  const int qrow = wv*16 + mi;
  const int srow = lane >> 3;

  const short* kg = kb  + bh*1024*64;
  const short* vg = vtb + bh*64*1024;

#define STAGE(Kd, Vd, stp) do{                                             \
    const short* kt_ = kg + (stp)*4096;                                    \
    _Pragma("unroll")                                                      \
    for (int i_ = 0; i_ < 2; i_++){                                        \
      int slab_ = wv*2 + i_, rbase_ = slab_*8;                             \
      int row_ = rbase_ + srow;                                            \
      int c_ = (lane & 7) ^ (row_ & 7);                                    \
      gl2lds16(kt_ + row_*64 + c_*8, (Kd) + rbase_*64 + lane*8);           \
      gl2lds16(vg + row_*1024 + (stp)*64 + c_*8, (Vd) + rbase_*64 + lane*8);\
    }                                                                      \
  }while(0)

  // prologue stage: Qt + K/V step 0 (distinct regions, drained at B1)
  {
    const short* qg = qb + (bh*1024 + n0)*64;
#pragma unroll
    for (int i = 0; i < 2; i++){
      int slab = wv*2 + i, rbase = slab*8;
      int row = rbase + srow;
      int c = (lane & 7) ^ (row & 7);
      gl2lds16(qg + row*64 + c*8, Qt + rbase*64 + lane*8);
    }
    STAGE(Kt0, Vt0, 0);
  }
  __syncthreads();   // B1: Qt + K0/V0 resident

  bf16x8 qf0 = *(const bf16x8*)(Qt + qrow*64 + sw0);
  bf16x8 qf1 = *(const bf16x8*)(Qt + qrow*64 + sw1);

  // rel_h -> rHs (wave-private columns wv*16+mi); h uniform per wave
  {
    int h = (n0 + wv*16) >> 5;
    const short* rp = rphb + (h + 31 - mi)*64;       // A row mi <-> kh = khb*16+mi
#pragma unroll
    for (int khb = 0; khb < 2; khb++){
      const short* rk = rp - khb*1024;               // -16 rows
      bf16x8 a0 = *(const bf16x8*)(rk + quad*8);
      bf16x8 a1 = *(const bf16x8*)(rk + 32 + quad*8);
      f32x4 c = {};
      c = mfma16(a0, qf0, c);
      c = mfma16(a1, qf1, c);
      for (int r = 0; r < 4; r++)
        rHs[(khb*16 + quad*4 + r)*64 + wv*16 + mi] = c[r] - MOFF;
    }
  }

  __syncthreads();   // B2: all waves done reading Qt before Es overwrites it

  // rel_w table: E[j'][qrow] = sum_d rpw8[j'][d] * q[qrow][d], j' = 0..63
  // (row 63 zero-padded, never read).  A row mi <-> j' = jt*16+mi.
#pragma unroll
  for (int jt = 0; jt < 4; jt++){
    const short* rr = rpwb + (jt*16 + mi)*64;
    bf16x8 a0 = *(const bf16x8*)(rr + quad*8);
    bf16x8 a1 = *(const bf16x8*)(rr + 32 + quad*8);
    f32x4 c = {};
    c = mfma16(a0, qf0, c);
    c = mfma16(a1, qf1, c);
    for (int r = 0; r < 4; r++)
      Es[(jt*16 + quad*4 + r)*64 + qrow] = c[r];
  }
  // gather per-lane rel_w (own-wave columns -> same-wave DS ordering)
  float rw[2][4];
  {
    int w31 = (qrow & 31) + 31;                      // w = (n0+qrow)&31
#pragma unroll
    for (int s = 0; s < 2; s++)
      for (int r = 0; r < 4; r++)
        rw[s][r] = Es[(w31 - (s*16 + quad*4 + r))*64 + qrow];
  }

  __syncthreads();   // B3: Es reads done before Kt1/Vt1 staging overwrites it

  f32x4 O[4] = {};
  float l_ = 0.f;

#define COMPUTE(Kb_, Vb_, stp) do{                                          \
    f32x4 S_[4];                                                            \
    _Pragma("unroll")                                                       \
    for (int nt = 0; nt < 4; nt++){                                         \
      bf16x8 kf0 = *(const bf16x8*)((Kb_) + (nt*16 + mi)*64 + sw0);         \
      bf16x8 kf1 = *(const bf16x8*)((Kb_) + (nt*16 + mi)*64 + sw1);         \
      f32x4 c_ = {};                                                        \
      c_ = mfma16(kf0, qf0, c_);                                            \
      c_ = mfma16(kf1, qf1, c_);                                            \
      S_[nt] = c_;                                                          \
    }                                                                       \
    float kh0_ = rHs[(2*(stp))*64 + qrow];                                  \
    float kh1_ = rHs[(2*(stp) + 1)*64 + qrow];                              \
    _Pragma("unroll")                                                       \
    for (int nt = 0; nt < 4; nt++){                                         \
      float kh_ = (nt & 2) ? kh1_ : kh0_;                                   \
      for (int r = 0; r < 4; r++){                                          \
        float p_ = __builtin_amdgcn_exp2f(S_[nt][r] + kh_ + rw[nt & 1][r]); \
        S_[nt][r] = p_;                                                     \
        l_ += p_;                                                           \
      }                                                                     \
    }                                                                       \
    _Pragma("unroll")                                                       \
    for (int nt = 0; nt < 4; nt++){                                         \
      unsigned u0_ = pk2(S_[nt][0], S_[nt][1]);                             \
      unsigned u1_ = pk2(S_[nt][2], S_[nt][3]);                             \
      int chunk_ = (2*nt + (quad >> 1)) ^ (mi & 7);                         \
      uint2 uu_; uu_.x = u0_; uu_.y = u1_;                                  \
      *(uint2*)(Pt + qrow*64 + chunk_*8 + (quad & 1)*4) = uu_;              \
    }                                                                       \
    bf16x8 p0_ = *(const bf16x8*)(Pt + qrow*64 + sw0);                      \
    bf16x8 p1_ = *(const bf16x8*)(Pt + qrow*64 + sw1);                      \
    _Pragma("unroll")                                                       \
    for (int t = 0; t < 4; t++){                                            \
      bf16x8 v0_ = *(const bf16x8*)((Vb_) + (t*16 + mi)*64 + sw0);          \
      bf16x8 v1_ = *(const bf16x8*)((Vb_) + (t*16 + mi)*64 + sw1);          \
      O[t] = mfma16(p0_, v0_, O[t]);                                        \
      O[t] = mfma16(p1_, v1_, O[t]);                                        \
    }                                                                       \
  }while(0)

  // 8 pairs: {stage 2s+1 -> buf1, compute 2s from buf0, barrier,
  //           stage 2s+2 -> buf0, compute 2s+1 from buf1, barrier}
#pragma unroll 1
  for (int s2 = 0; s2 < 8; s2++){
    STAGE(Kt1, Vt1, 2*s2 + 1);
    COMPUTE(Kt0, Vt0, 2*s2);
    __syncthreads();                       // buf1 staged; buf0 reads done
    if (s2 < 7) STAGE(Kt0, Vt0, 2*s2 + 2);
    COMPUTE(Kt1, Vt1, 2*s2 + 1);
    if (s2 < 7) __syncthreads();           // buf0 staged; buf1 reads done
  }
#undef STAGE
#undef COMPUTE

  l_ += __shfl_xor(l_, 16, 64);
  l_ += __shfl_xor(l_, 32, 64);
  float inv[4];
#pragma unroll
  for (int r = 0; r < 4; r++) inv[r] = 1.f / __shfl(l_, quad*4 + r, 64);
  int b_ = bh / 12, head = bh % 12;
#pragma unroll
  for (int t = 0; t < 4; t++)
    for (int r = 0; r < 4; r++){
      int n = n0 + wv*16 + quad*4 + r;
      ao[(b_*1024 + n)*768 + head*64 + t*16 + mi] = (short)f2bf(O[t][r] * inv[r]);
    }
}

// ---------------------------------------------------------------- out proj
// 64x96 tiles -> grid 64x8 = 512 blocks = exactly 2/CU.
__global__ __launch_bounds__(256) void proj_kernel(const short* __restrict__ ao,
                                                   const short* __restrict__ woT,
                                                   const float* __restrict__ bias,
                                                   float* __restrict__ out){
  __shared__ __align__(16) short As[64*64];
  __shared__ __align__(16) short Bs[96*64];
  const int tid = threadIdx.x, lane = tid & 63, wv = tid >> 6;
  const int quad = lane >> 4, mi = lane & 15;
  const int m0 = blockIdx.x * 64, n0 = blockIdx.y * 96;
  const int wrow = wv >> 1, wcol = wv & 1;         // wave tile: 32 rows x 48 cols
  const int srow = lane >> 3, sc = (lane & 7) ^ (srow & 7);
  f32x4 acc[2][3] = {};
  for (int k0 = 0; k0 < 768; k0 += 64){
    __syncthreads();
    for (int i = 0; i < 2; i++){
      int rbase = i*32 + wv*8, row = rbase + srow;
      gl2lds16(ao + (m0+row)*768 + k0 + sc*8, As + rbase*64 + lane*8);
    }
    for (int i = 0; i < 3; i++){
      int rbase = i*32 + wv*8, row = rbase + srow;
      gl2lds16(woT + (n0+row)*768 + k0 + sc*8, Bs + rbase*64 + lane*8);
    }
    __syncthreads();
    bf16x8 a[2][2], b[2][3];
#pragma unroll
    for (int kk = 0; kk < 2; kk++){
      int ccs = ((quad + kk*4) ^ (mi & 7)) * 8;
      for (int mt = 0; mt < 2; mt++) a[kk][mt] = *(const bf16x8*)(As + (wrow*32 + mt*16 + mi)*64 + ccs);
      for (int nt = 0; nt < 3; nt++) b[kk][nt] = *(const bf16x8*)(Bs + (wcol*48 + nt*16 + mi)*64 + ccs);
    }
#pragma unroll
    for (int kk = 0; kk < 2; kk++)
      for (int mt = 0; mt < 2; mt++)
        for (int nt = 0; nt < 3; nt++)
          acc[mt][nt] = mfma16(a[kk][mt], b[kk][nt], acc[mt][nt]);
  }
  for (int nt = 0; nt < 3; nt++){
    int j = n0 + wcol*48 + nt*16 + mi;
    float bj = bias[j];
    for (int mt = 0; mt < 2; mt++)
      for (int r = 0; r < 4; r++){
        int m = m0 + wrow*32 + mt*16 + quad*4 + r;
        out[m*768 + j] = acc[mt][nt][r] + bj;
      }
  }
}

// ---------------------------------------------------------------- launch
extern "C" void kernel_launch(void* const* d_in, const int* in_sizes, int n_in,
                              void* d_out, int out_size, void* d_ws, size_t ws_size,
                              hipStream_t stream){
  const float* x     = (const float*)d_in[0];
  const float* w_qkv = (const float*)d_in[1];
  const float* w_out = (const float*)d_in[2];
  const float* b_out = (const float*)d_in[3];
  const float* rph   = (const float*)d_in[4];
  const float* rpw   = (const float*)d_in[5];
  float* out = (float*)d_out;
  char* ws = (char*)d_ws;
  short* xb    = (short*)(ws + 0);          // 4096x768 bf16 (reused as ao after qkv)
  short* wqT   = (short*)(ws + 6291456);    // 2304x768 bf16
  short* woT   = (short*)(ws + 9830400);    // 768x768 bf16
  short* qb    = (short*)(ws + 11010048);   // 48x1024x64 bf16 (pre-scaled 0.125*log2e)
  short* kb    = (short*)(ws + 17301504);   // 48x1024x64 bf16
  short* vtb   = (short*)(ws + 29884416);   // 48x64x1024 bf16 (written by qkv, transposed)
  short* rphb  = (short*)(ws + 48758784);   // 63x64 bf16 (*8)
  short* rpwb  = (short*)(ws + 48775168);   // 64x64 bf16 (*8, row 63 zeroed)
  short* ao    = xb;                        // reuse

  prep_kernel<<<3841, 256, 0, stream>>>(x, xb, rph, rpw, rphb, rpwb, w_qkv, wqT, w_out, woT);
  qkv_gemm_kernel<<<dim3(32, 24), 256, 0, stream>>>(xb, wqT, qb, kb, vtb);
  flash_kernel<<<dim3(16, 48), 256, 0, stream>>>(qb, kb, vtb, rphb, rpwb, ao);
  proj_kernel<<<dim3(64, 8), 256, 0, stream>>>(ao, woT, b_out, out);
}